// Round 2
// baseline (496.215 us; speedup 1.0000x reference)
//
#include <hip/hip_runtime.h>
#include <cmath>

// PhaseAwareClassifier on MI355X — R19: 16-wave blocks (4 waves/SIMD).
// R18 post-mortem: step = GEMM phase (LDS 6.1k cyc + ~4k latency stalls at
// only 3 waves/SIMD) + barrier-serialized epilogue (~3.7k VALU cyc). MFMA
// issue is only ~12%. VGPR stayed 84 and 15.5 MB scratch writes appeared ->
// R18's big register cache partially backfired. Fixes:
//  1) 1024-thread blocks, 16 waves, 4 waves/SIMD (VGPR cap 128): doubles
//     latency-hiding in the GEMM phase. (mg,ng) = (4,4); mg0..2 own 2
//     M-tiles, mg3 owns tiles {6,7,8} so t=9 energy rows 121..130 and the
//     t=9 path live in one branch. Injection rows <49 -> mg0/mg1.
//  2) A-register cache trimmed to kt0/kt1 x mt0/mt1 (8 frags, 32 VGPR,
//     uniform); mg3's tile-8 frags come from LDS. Keeps pressure ~115.
//  3) Epilogue algebra: fold 0.25 into stored gain (g2q = g2/4);
//     out = a*tanh'*rsqrt(a^2+b^2+1.6e-7). Bit-exact (all rescales are
//     powers of 2; fma/rcp/rsq rounding sequence verified identical).
//  4) t=9: barrier between mg3's CrL A-reads and scrE writes (scrE aliases
//     CrL chunks 0..2, which mg3 now reads at t=9 kt0 for tile 8).
// Discipline kept: unroll(1) on LDS kt-loop (R15), constant acc indices
// (rule #20), no forced reg caps beyond launch_bounds. LDS 156,672 B.

#define NSTEPS  10
#define INJ_ST  4
#define MT      144          // padded M (9 tiles of 16)

typedef __bf16 bf16x8 __attribute__((ext_vector_type(8)));
typedef __bf16 bf16x4 __attribute__((ext_vector_type(4)));
typedef short  short8 __attribute__((ext_vector_type(8)));
typedef float  f32x4  __attribute__((ext_vector_type(4)));

// workspace layout (float offsets)
#define WS_MAX    0          // 1      enc_max (uint-ordered float)
#define WS_ENERGY 64         // 1280   energy[b][10]
#define WS_GSP    2048       // 144    g2q[j] = -0.5*log2(e)*softplus(gain)
#define WS_CONN   4096       // 2 bf16 mats [20][144][8] chunked: Cr, Ci
#define WS_INJ    32768      // 100352 inj[b][49][16] = px * 1.02/enc_max

__global__ void k_init(float* ws) {
    int i = blockIdx.x * 256 + threadIdx.x;
    if (i == 0) ws[WS_MAX] = 0.f;
    if (i < 1280) ws[WS_ENERGY + i] = 0.f;
}

__global__ void k_max(const float* __restrict__ img, float* ws, int n) {
    __shared__ float sm[256];
    float v = 0.f;
    for (int i = blockIdx.x * blockDim.x + threadIdx.x; i < n; i += gridDim.x * blockDim.x)
        v = fmaxf(v, fabsf(img[i]));
    sm[threadIdx.x] = v;
    __syncthreads();
    for (int s = 128; s > 0; s >>= 1) {
        if (threadIdx.x < s) sm[threadIdx.x] = fmaxf(sm[threadIdx.x], sm[threadIdx.x + s]);
        __syncthreads();
    }
    if (threadIdx.x == 0)
        atomicMax((unsigned int*)(ws + WS_MAX), __float_as_uint(sm[0]));
}

__global__ void k_prep(const float* __restrict__ img,
                       const float* __restrict__ cr, const float* __restrict__ ci,
                       const float* __restrict__ phase, const float* __restrict__ gain,
                       float* ws) {
    int i = blockIdx.x * 256 + threadIdx.x;
    __bf16* Cb = (__bf16*)(ws + WS_CONN);
    const int NCE = MT * 160;              // 23040 (m,k) pairs
    if (i < NCE) {
        int m = i / 160, k = i % 160;
        float vr = 0.f, vi = 0.f;
        if (m < 131 && k < 131) {
            float a = cr[k * 131 + m], b = ci[k * 131 + m];
            float ph = phase[m];
            float cp = cosf(ph), sp = sinf(ph);
            vr = a * cp - b * sp;
            vi = a * sp + b * cp;
        }
        int ca = ((k >> 3) * MT + m) * 8 + (k & 7);    // chunked addr
        Cb[ca]       = (__bf16)vr;
        Cb[NCE + ca] = (__bf16)vi;
    } else if (i < NCE + MT) {
        int j = i - NCE;
        float g = 0.f;
        if (j < 131) {
            float x = gain[j];
            g = (x > 20.f) ? x : log1pf(expf(x));  // softplus
        }
        ws[WS_GSP + j] = g * -0.72134754543f;       // -2*log2(e)*g / 4
    } else if (i < NCE + MT + 128 * 49 * 16) {
        int q = i - NCE - MT;
        int m = q & 15, jj = (q >> 4) % 49, b = q / (49 * 16);
        int u = m >> 2, v2 = m & 3, pi = jj / 7, pj = jj % 7;
        float px = img[b * 784 + (pi * 4 + u) * 28 + (pj * 4 + v2)];
        float mx = ws[WS_MAX];
        float sc = (mx > 1e-8f) ? (1.02f / mx) : 1.02f;   // 0.85*4*0.3
        ws[WS_INJ + q] = px * sc;
    }
}

static __device__ __forceinline__ f32x4 MF(bf16x8 a, bf16x8 b, f32x4 c) {
    return __builtin_amdgcn_mfma_f32_16x16x32_bf16(a, b, c, 0, 0, 0);
}
static __device__ __forceinline__ bf16x8 bneg(bf16x8 a) {
    short8 t = __builtin_bit_cast(short8, a) ^ (short8)(short)0x8000;
    return __builtin_bit_cast(bf16x8, t);
}

// one complex 16x16 tile accumulation; order identical to R17/R18.
#define CPAIR(AR, AI, BR, BI, BNI, P)                                  \
    accr[P] = MF(AR, BR,  accr[P]);                                    \
    accr[P] = MF(AI, BNI, accr[P]);                                    \
    acci[P] = MF(AR, BI,  acci[P]);                                    \
    acci[P] = MF(AI, BR,  acci[P]);

__global__ __launch_bounds__(1024, 4)
void k_main(const float* __restrict__ ws, float* __restrict__ energy) {
    __shared__ __bf16 OB[2][18 * 128 * 8];         // 73,728 B: Or, Oi (18 ch)
    __shared__ __bf16 CrL[18 * MT * 8];            // 41,472 B: Cr (18 ch)
    __shared__ __bf16 CiL[18 * MT * 8];            // 41,472 B: Ci (18 ch)
    // total 156,672 B -> 1 block/CU, 16 waves = 4/SIMD.
    const int tid  = threadIdx.x;
    const int lane = tid & 63;
    const int ln15 = lane & 15;
    const int quad = lane >> 4;
    const int wv   = __builtin_amdgcn_readfirstlane(tid >> 6);  // 0..15
    const int mg   = wv >> 2;                       // 0..3
    const int ng   = wv & 3;                        // N-tiles 2ng, 2ng+1
    const int rb   = 32 * mg;                       // M-row base (mg3: +tile 8)
    const int b    = blockIdx.x >> 3;               // 8 blocks per image
    const int m    = ln15;

    const float* __restrict__ gsp2 = ws + WS_GSP;
    const float* __restrict__ injb = ws + WS_INJ;

    __bf16* __restrict__ OBr = &OB[0][0];
    __bf16* __restrict__ OBi = &OB[1][0];
    float* scrE = (float*)CrL;                      // alias: end only (t=9)

    // per-position encoding weight (pn = 0,1)
    float wls[2];
#pragma unroll
    for (int q = 0; q < 2; ++q) {
        int l = ((blockIdx.x & 7) * 8 + 2 * ng + q) & 63;
        wls[q] = 1.0f - fabsf((float)l - 32.0f) * (1.0f / 64.0f);
    }

    // stage Cr, Ci (chunks 0..17) -> LDS. No OB zero-init: t=0 epilogue
    // writes every OB cell (rows 0..143 across mg, all 128 cols).
    {
        const int4* srcR = (const int4*)(ws + WS_CONN);
        const int4* srcI = (const int4*)(ws + WS_CONN + (MT * 160 / 2)); // +20ch
        int4* dstR = (int4*)CrL;
        int4* dstI = (int4*)CiL;
        for (int i = tid; i < 2592; i += 1024) { dstR[i] = srcR[i]; dstI[i] = srcI[i]; }
    }

    f32x4 accr[6], acci[6];                         // p = mt*2 + pn, mt 0..2
#pragma unroll
    for (int p = 0; p < 6; ++p) { accr[p] = (f32x4)0.f; acci[p] = (f32x4)0.f; }

    // injection: rows j<49 live in mg0 (rows 0..31) and mg1 (rows 32..48)
    auto inj_add = [&]() {
        if (mg <= 1) {
#pragma unroll
            for (int p = 0; p < 4; ++p) {
                const int j0 = rb + (p >> 1) * 16 + quad * 4;
#pragma unroll
                for (int r = 0; r < 4; ++r) {
                    int j = j0 + r;
                    if (j < 49) accr[p][r] += injb[(b * 49 + j) * 16 + m] * wls[p & 1];
                }
            }
        }
    };

    // epilogue: out = a * tanh(g*|f|)/|f| with 0.25 folded into g2q.
    // Bit-exact vs R18 form (pow2 rescales only).
    auto epi_one = [&](int p, int j0) {
        const int n = (2 * ng + (p & 1)) * 16 + ln15;
        float g2[4];
        *(float4*)g2 = *(const float4*)(gsp2 + j0);
        bf16x4 pr, pi;
#pragma unroll
        for (int r = 0; r < 4; ++r) {
            float ar = accr[p][r], ai = acci[p][r];
            float mag2 = fmaf(ar, ar, fmaf(ai, ai, 1.6e-7f));
            float rsq  = __builtin_amdgcn_rsqf(mag2);
            float e    = __builtin_amdgcn_exp2f(g2[r] * (mag2 * rsq));
            float u    = __builtin_amdgcn_rcpf(1.0f + e);
            float th   = fmaf(-2.0f, e * u, 1.0f);
            float scv  = th * rsq;
            pr[r] = (__bf16)(ar * scv); pi[r] = (__bf16)(ai * scv);
        }
        const int off = ((j0 >> 3) * 128 + n) * 8 + (j0 & 7);
        *(bf16x4*)(OBr + off) = pr;
        *(bf16x4*)(OBi + off) = pi;
    };
    auto epilogue = [&]() {
#pragma unroll
        for (int p = 0; p < 4; ++p) epi_one(p, rb + (p >> 1) * 16 + quad * 4);
        if (mg == 3) {
#pragma unroll
            for (int p = 4; p < 6; ++p) epi_one(p, 128 + quad * 4);
        }
    };

    __syncthreads();                                // CrL/CiL staged

    // A-register cache: kt0 (chunk quad) and kt1 (chunk 4+quad), mt0/mt1.
    // 8 frags = 32 VGPR, uniform across waves (mg3 tile-8 reads stay in LDS).
    bf16x8 cR[2][2], cI[2][2];
#pragma unroll
    for (int k = 0; k < 2; ++k) {
        const int ab = ((4 * k + quad) * MT + rb + ln15) * 8;
#pragma unroll
        for (int mt = 0; mt < 2; ++mt) {
            cR[k][mt] = *(const bf16x8*)(CrL + ab + 128 * mt);
            cI[k][mt] = *(const bf16x8*)(CiL + ab + 128 * mt);
        }
    }

    inj_add();                                      // t = 0 (out is zero)
    epilogue();
    __syncthreads();

    for (int t = 1; t < NSTEPS - 1; ++t) {
#pragma unroll
        for (int p = 0; p < 6; ++p) { accr[p] *= 0.85f; acci[p] *= 0.85f; }
        if (t < INJ_ST) inj_add();

        // mg3 tile-8 A-frags for kt0,1 (from LDS, per step; 4 reads)
        bf16x8 a2r[2], a2i[2];
        if (mg == 3) {
#pragma unroll
            for (int k = 0; k < 2; ++k) {
                const int ab = ((4 * k + quad) * MT + 128 + ln15) * 8;
                a2r[k] = *(const bf16x8*)(CrL + ab);
                a2i[k] = *(const bf16x8*)(CiL + ab);
            }
        }

        // ---- kt = 0,1: A from registers (+LDS tile 8), B from LDS ----
#pragma unroll
        for (int pn = 0; pn < 2; ++pn) {
            const int nb = ((2 * ng + pn) * 16 + ln15) * 8;
            {
                bf16x8 br = *(const bf16x8*)(OBr + quad * 1024 + nb);
                bf16x8 bi = *(const bf16x8*)(OBi + quad * 1024 + nb);
                bf16x8 bn = bneg(bi);
                CPAIR(cR[0][0], cI[0][0], br, bi, bn, pn)
                CPAIR(cR[0][1], cI[0][1], br, bi, bn, 2 + pn)
                if (mg == 3) { CPAIR(a2r[0], a2i[0], br, bi, bn, 4 + pn) }
            }
            {
                bf16x8 br = *(const bf16x8*)(OBr + (4 + quad) * 1024 + nb);
                bf16x8 bi = *(const bf16x8*)(OBi + (4 + quad) * 1024 + nb);
                bf16x8 bn = bneg(bi);
                CPAIR(cR[1][0], cI[1][0], br, bi, bn, pn)
                CPAIR(cR[1][1], cI[1][1], br, bi, bn, 2 + pn)
                if (mg == 3) { CPAIR(a2r[1], a2i[1], br, bi, bn, 4 + pn) }
            }
        }

        // ---- kt = 2..4: LDS path. Skipped at t=1 (out(0) rows >=49 are
        // exactly zero). kch 18,19 remap to chunk 17 (zeros on the A side).
        if (t > 1) {
#pragma unroll 1
            for (int kt = 2; kt < 5; ++kt) {
                const int kch = kt * 4 + quad;
                const int rk  = (kch > 17) ? 17 : kch;
                const int ab  = (rk * MT + rb + ln15) * 8;
                bf16x8 ar0 = *(const bf16x8*)(CrL + ab);
                bf16x8 ar1 = *(const bf16x8*)(CrL + ab + 128);
                bf16x8 ai0 = *(const bf16x8*)(CiL + ab);
                bf16x8 ai1 = *(const bf16x8*)(CiL + ab + 128);
                bf16x8 ar2, ai2;
                if (mg == 3) {
                    ar2 = *(const bf16x8*)(CrL + ab + 256);
                    ai2 = *(const bf16x8*)(CiL + ab + 256);
                }
#pragma unroll
                for (int pn = 0; pn < 2; ++pn) {
                    const int boff = (rk * 128 + (2 * ng + pn) * 16 + ln15) * 8;
                    bf16x8 br = *(const bf16x8*)(OBr + boff);
                    bf16x8 bi = *(const bf16x8*)(OBi + boff);
                    bf16x8 bn = bneg(bi);
                    CPAIR(ar0, ai0, br, bi, bn, pn)
                    CPAIR(ar1, ai1, br, bi, bn, 2 + pn)
                    if (mg == 3) { CPAIR(ar2, ai2, br, bi, bn, 4 + pn) }
                }
            }
        }
        __syncthreads();   // all reads of OB done
        epilogue();
        __syncthreads();   // OB ready
    }

    // ---- t = 9: only rows 121..130 (tiles 7,8 = mg3 mt1,mt2) feed energy.
    if (mg == 3) {
#pragma unroll
        for (int p = 2; p < 6; ++p) { accr[p] *= 0.85f; acci[p] *= 0.85f; }
        bf16x8 a2r[2], a2i[2];
#pragma unroll
        for (int k = 0; k < 2; ++k) {
            const int ab = ((4 * k + quad) * MT + 128 + ln15) * 8;
            a2r[k] = *(const bf16x8*)(CrL + ab);
            a2i[k] = *(const bf16x8*)(CiL + ab);
        }
#pragma unroll
        for (int pn = 0; pn < 2; ++pn) {
            const int nb = ((2 * ng + pn) * 16 + ln15) * 8;
            {
                bf16x8 br = *(const bf16x8*)(OBr + quad * 1024 + nb);
                bf16x8 bi = *(const bf16x8*)(OBi + quad * 1024 + nb);
                bf16x8 bn = bneg(bi);
                CPAIR(cR[0][1], cI[0][1], br, bi, bn, 2 + pn)
                CPAIR(a2r[0], a2i[0], br, bi, bn, 4 + pn)
            }
            {
                bf16x8 br = *(const bf16x8*)(OBr + (4 + quad) * 1024 + nb);
                bf16x8 bi = *(const bf16x8*)(OBi + (4 + quad) * 1024 + nb);
                bf16x8 bn = bneg(bi);
                CPAIR(cR[1][1], cI[1][1], br, bi, bn, 2 + pn)
                CPAIR(a2r[1], a2i[1], br, bi, bn, 4 + pn)
            }
        }
#pragma unroll 1
        for (int kt = 2; kt < 5; ++kt) {
            const int kch = kt * 4 + quad;
            const int rk  = (kch > 17) ? 17 : kch;
            const int ab  = (rk * MT + 96 + ln15) * 8;     // rb = 96
            bf16x8 ar1 = *(const bf16x8*)(CrL + ab + 128);
            bf16x8 ar2 = *(const bf16x8*)(CrL + ab + 256);
            bf16x8 ai1 = *(const bf16x8*)(CiL + ab + 128);
            bf16x8 ai2 = *(const bf16x8*)(CiL + ab + 256);
#pragma unroll
            for (int pn = 0; pn < 2; ++pn) {
                const int boff = (rk * 128 + (2 * ng + pn) * 16 + ln15) * 8;
                bf16x8 br = *(const bf16x8*)(OBr + boff);
                bf16x8 bi = *(const bf16x8*)(OBi + boff);
                bf16x8 bn = bneg(bi);
                CPAIR(ar1, ai1, br, bi, bn, 2 + pn)
                CPAIR(ar2, ai2, br, bi, bn, 4 + pn)
            }
        }
    }
    __syncthreads();       // mg3's CrL A-reads done before scrE (alias) writes

    if (mg == 3) {
        // energy rows: fp32 |out|^2 -> scrE (aliases CrL chunks 0..2)
#pragma unroll
        for (int p = 2; p < 6; ++p) {
            const int j0 = (p < 4) ? (112 + quad * 4) : (128 + quad * 4);
            const int n  = (2 * ng + (p & 1)) * 16 + ln15;
            float g2[4];
            *(float4*)g2 = *(const float4*)(gsp2 + j0);
#pragma unroll
            for (int r = 0; r < 4; ++r) {
                int j = j0 + r;
                if (j >= 121 && j <= 130) {
                    float ar = accr[p][r], ai = acci[p][r];
                    float mag2 = fmaf(ar, ar, fmaf(ai, ai, 1.6e-7f));
                    float rsq  = __builtin_amdgcn_rsqf(mag2);
                    float e    = __builtin_amdgcn_exp2f(g2[r] * (mag2 * rsq));
                    float u    = __builtin_amdgcn_rcpf(1.0f + e);
                    float th   = fmaf(-2.0f, e * u, 1.0f);
                    float scv  = th * rsq;
                    float orv = ar * scv, oiv = ai * scv;
                    scrE[(j - 121) * 128 + n] = orv * orv + oiv * oiv;
                }
            }
        }
    }
    __syncthreads();       // scrE complete

    // ---- energy: scrE[10][128] holds exact fp32 |out|^2 ----
    if (tid < 10) {
        float ssum = 0.f;
        for (int cc = 0; cc < 128; ++cc) ssum += scrE[tid * 128 + cc];
        atomicAdd(energy + b * 10 + tid, ssum);
    }
}

__global__ void k_readout(const float* __restrict__ ws,
                          const float* __restrict__ W,
                          const float* __restrict__ bias,
                          float* __restrict__ out) {
    int i = blockIdx.x * 256 + threadIdx.x;
    if (i < 1280) {
        int b = i / 10, o = i % 10;
        float s = bias[o];
#pragma unroll
        for (int f = 0; f < 10; ++f) {
            float feat = log1pf(ws[WS_ENERGY + b * 10 + f] + 1e-8f);
            s = fmaf(feat, W[o * 10 + f], s);
        }
        out[i] = s;
    }
}

extern "C" void kernel_launch(void* const* d_in, const int* in_sizes, int n_in,
                              void* d_out, int out_size, void* d_ws, size_t ws_size,
                              hipStream_t stream) {
    const float* images = (const float*)d_in[0];
    const float* conn_r = (const float*)d_in[1];
    const float* conn_i = (const float*)d_in[2];
    const float* phase  = (const float*)d_in[3];
    const float* gain   = (const float*)d_in[4];
    const float* W      = (const float*)d_in[5];
    const float* bias   = (const float*)d_in[6];
    float* ws  = (float*)d_ws;
    float* out = (float*)d_out;

    hipLaunchKernelGGL(k_init, dim3(6), dim3(256), 0, stream, ws);
    hipLaunchKernelGGL(k_max, dim3(98), dim3(256), 0, stream, images, ws, 128 * 28 * 28);
    hipLaunchKernelGGL(k_prep, dim3(484), dim3(256), 0, stream,
                       images, conn_r, conn_i, phase, gain, ws);
    hipLaunchKernelGGL(k_main, dim3(1024), dim3(1024), 0, stream, ws, ws + WS_ENERGY);
    hipLaunchKernelGGL(k_readout, dim3(5), dim3(256), 0, stream, ws, W, bias, out);
}

// Round 3
// 284.562 us; speedup vs baseline: 1.7438x; 1.7438x over previous
//
#include <hip/hip_runtime.h>
#include <cmath>

// PhaseAwareClassifier on MI355X — R20: 16 waves, clean launch bounds.
// R19 post-mortem: __launch_bounds__(1024, 4) drove the allocator to a
// 64-VGPR budget -> ~280 B/thread of IN-LOOP scratch (FETCH/WRITE 215/225 MB,
// 30 ms scratch-zero fill) -> 454 us. The 16-wave structure itself was never
// tested. R18's 15.5 MB WRITE was ~20 B/thread = once-per-thread spill (free).
// R20 = R19 structure with:
//  1) __launch_bounds__(1024) ONLY: flat-WG-size forces VGPR<=128 for
//     launchability without pushing the allocator below it.
//  2) A-register cache removed entirely (all A-frags from LDS, uniform kt
//     loop 0..ktEnd): worst wave ~105 VGPR, well under the 128 cap.
//  3) Decay only on live acc pairs (mg<3: p0..3; mg3: all 6).
// Bit-exact vs R18/R19: per-accumulator MFMA chain order unchanged (kt
// ascending, same CPAIR order); t=1 kt<2 (out(0) rows>=49 exactly zero);
// t=9 mg3-only tail. Discipline: unroll(1) on kt loop (R15), constant acc
// indices (rule #20). LDS 156,672 B -> 1 block/CU, 16 waves = 4/SIMD.

#define NSTEPS  10
#define INJ_ST  4
#define MT      144          // padded M (9 tiles of 16)

typedef __bf16 bf16x8 __attribute__((ext_vector_type(8)));
typedef __bf16 bf16x4 __attribute__((ext_vector_type(4)));
typedef short  short8 __attribute__((ext_vector_type(8)));
typedef float  f32x4  __attribute__((ext_vector_type(4)));

// workspace layout (float offsets)
#define WS_MAX    0          // 1      enc_max (uint-ordered float)
#define WS_ENERGY 64         // 1280   energy[b][10]
#define WS_GSP    2048       // 144    g2q[j] = -0.5*log2(e)*softplus(gain)
#define WS_CONN   4096       // 2 bf16 mats [20][144][8] chunked: Cr, Ci
#define WS_INJ    32768      // 100352 inj[b][49][16] = px * 1.02/enc_max

__global__ void k_init(float* ws) {
    int i = blockIdx.x * 256 + threadIdx.x;
    if (i == 0) ws[WS_MAX] = 0.f;
    if (i < 1280) ws[WS_ENERGY + i] = 0.f;
}

__global__ void k_max(const float* __restrict__ img, float* ws, int n) {
    __shared__ float sm[256];
    float v = 0.f;
    for (int i = blockIdx.x * blockDim.x + threadIdx.x; i < n; i += gridDim.x * blockDim.x)
        v = fmaxf(v, fabsf(img[i]));
    sm[threadIdx.x] = v;
    __syncthreads();
    for (int s = 128; s > 0; s >>= 1) {
        if (threadIdx.x < s) sm[threadIdx.x] = fmaxf(sm[threadIdx.x], sm[threadIdx.x + s]);
        __syncthreads();
    }
    if (threadIdx.x == 0)
        atomicMax((unsigned int*)(ws + WS_MAX), __float_as_uint(sm[0]));
}

__global__ void k_prep(const float* __restrict__ img,
                       const float* __restrict__ cr, const float* __restrict__ ci,
                       const float* __restrict__ phase, const float* __restrict__ gain,
                       float* ws) {
    int i = blockIdx.x * 256 + threadIdx.x;
    __bf16* Cb = (__bf16*)(ws + WS_CONN);
    const int NCE = MT * 160;              // 23040 (m,k) pairs
    if (i < NCE) {
        int m = i / 160, k = i % 160;
        float vr = 0.f, vi = 0.f;
        if (m < 131 && k < 131) {
            float a = cr[k * 131 + m], b = ci[k * 131 + m];
            float ph = phase[m];
            float cp = cosf(ph), sp = sinf(ph);
            vr = a * cp - b * sp;
            vi = a * sp + b * cp;
        }
        int ca = ((k >> 3) * MT + m) * 8 + (k & 7);    // chunked addr
        Cb[ca]       = (__bf16)vr;
        Cb[NCE + ca] = (__bf16)vi;
    } else if (i < NCE + MT) {
        int j = i - NCE;
        float g = 0.f;
        if (j < 131) {
            float x = gain[j];
            g = (x > 20.f) ? x : log1pf(expf(x));  // softplus
        }
        ws[WS_GSP + j] = g * -0.72134754543f;       // -2*log2(e)*g / 4
    } else if (i < NCE + MT + 128 * 49 * 16) {
        int q = i - NCE - MT;
        int m = q & 15, jj = (q >> 4) % 49, b = q / (49 * 16);
        int u = m >> 2, v2 = m & 3, pi = jj / 7, pj = jj % 7;
        float px = img[b * 784 + (pi * 4 + u) * 28 + (pj * 4 + v2)];
        float mx = ws[WS_MAX];
        float sc = (mx > 1e-8f) ? (1.02f / mx) : 1.02f;   // 0.85*4*0.3
        ws[WS_INJ + q] = px * sc;
    }
}

static __device__ __forceinline__ f32x4 MF(bf16x8 a, bf16x8 b, f32x4 c) {
    return __builtin_amdgcn_mfma_f32_16x16x32_bf16(a, b, c, 0, 0, 0);
}
static __device__ __forceinline__ bf16x8 bneg(bf16x8 a) {
    short8 t = __builtin_bit_cast(short8, a) ^ (short8)(short)0x8000;
    return __builtin_bit_cast(bf16x8, t);
}

// one complex 16x16 tile accumulation; order identical to R17..R19.
#define CPAIR(AR, AI, BR, BI, BNI, P)                                  \
    accr[P] = MF(AR, BR,  accr[P]);                                    \
    accr[P] = MF(AI, BNI, accr[P]);                                    \
    acci[P] = MF(AR, BI,  acci[P]);                                    \
    acci[P] = MF(AI, BR,  acci[P]);

__global__ __launch_bounds__(1024)
void k_main(const float* __restrict__ ws, float* __restrict__ energy) {
    __shared__ __bf16 OB[2][18 * 128 * 8];         // 73,728 B: Or, Oi (18 ch)
    __shared__ __bf16 CrL[18 * MT * 8];            // 41,472 B: Cr (18 ch)
    __shared__ __bf16 CiL[18 * MT * 8];            // 41,472 B: Ci (18 ch)
    // total 156,672 B -> 1 block/CU, 16 waves = 4/SIMD.
    const int tid  = threadIdx.x;
    const int lane = tid & 63;
    const int ln15 = lane & 15;
    const int quad = lane >> 4;
    const int wv   = __builtin_amdgcn_readfirstlane(tid >> 6);  // 0..15
    const int mg   = wv >> 2;                       // 0..3
    const int ng   = wv & 3;                        // N-tiles 2ng, 2ng+1
    const int rb   = 32 * mg;                       // M-row base (mg3: 3 tiles)
    const int b    = blockIdx.x >> 3;               // 8 blocks per image
    const int m    = ln15;

    const float* __restrict__ gsp2 = ws + WS_GSP;
    const float* __restrict__ injb = ws + WS_INJ;

    __bf16* __restrict__ OBr = &OB[0][0];
    __bf16* __restrict__ OBi = &OB[1][0];
    float* scrE = (float*)CrL;                      // alias: end only (t=9)

    // per-position encoding weight (pn = 0,1)
    float wls[2];
#pragma unroll
    for (int q = 0; q < 2; ++q) {
        int l = ((blockIdx.x & 7) * 8 + 2 * ng + q) & 63;
        wls[q] = 1.0f - fabsf((float)l - 32.0f) * (1.0f / 64.0f);
    }

    // stage Cr, Ci (chunks 0..17) -> LDS. No OB zero-init: t=0 epilogue
    // writes every OB cell (rows 0..143 across mg, all 128 cols).
    {
        const int4* srcR = (const int4*)(ws + WS_CONN);
        const int4* srcI = (const int4*)(ws + WS_CONN + (MT * 160 / 2)); // +20ch
        int4* dstR = (int4*)CrL;
        int4* dstI = (int4*)CiL;
        for (int i = tid; i < 2592; i += 1024) { dstR[i] = srcR[i]; dstI[i] = srcI[i]; }
    }

    f32x4 accr[6], acci[6];                         // p = mt*2 + pn, mt 0..2
#pragma unroll
    for (int p = 0; p < 6; ++p) { accr[p] = (f32x4)0.f; acci[p] = (f32x4)0.f; }

    // injection: rows j<49 live in mg0 (rows 0..31) and mg1 (rows 32..48)
    auto inj_add = [&]() {
        if (mg <= 1) {
#pragma unroll
            for (int p = 0; p < 4; ++p) {
                const int j0 = rb + (p >> 1) * 16 + quad * 4;
#pragma unroll
                for (int r = 0; r < 4; ++r) {
                    int j = j0 + r;
                    if (j < 49) accr[p][r] += injb[(b * 49 + j) * 16 + m] * wls[p & 1];
                }
            }
        }
    };

    // epilogue: out = a * tanh(g*|f|)/|f| with 0.25 folded into g2q.
    auto epi_one = [&](int p, int j0) {
        const int n = (2 * ng + (p & 1)) * 16 + ln15;
        float g2[4];
        *(float4*)g2 = *(const float4*)(gsp2 + j0);
        bf16x4 pr, pi;
#pragma unroll
        for (int r = 0; r < 4; ++r) {
            float ar = accr[p][r], ai = acci[p][r];
            float mag2 = fmaf(ar, ar, fmaf(ai, ai, 1.6e-7f));
            float rsq  = __builtin_amdgcn_rsqf(mag2);
            float e    = __builtin_amdgcn_exp2f(g2[r] * (mag2 * rsq));
            float u    = __builtin_amdgcn_rcpf(1.0f + e);
            float th   = fmaf(-2.0f, e * u, 1.0f);
            float scv  = th * rsq;
            pr[r] = (__bf16)(ar * scv); pi[r] = (__bf16)(ai * scv);
        }
        const int off = ((j0 >> 3) * 128 + n) * 8 + (j0 & 7);
        *(bf16x4*)(OBr + off) = pr;
        *(bf16x4*)(OBi + off) = pi;
    };
    auto epilogue = [&]() {
#pragma unroll
        for (int p = 0; p < 4; ++p) epi_one(p, rb + (p >> 1) * 16 + quad * 4);
        if (mg == 3) {
#pragma unroll
            for (int p = 4; p < 6; ++p) epi_one(p, 128 + quad * 4);
        }
    };

    __syncthreads();                                // CrL/CiL staged

    inj_add();                                      // t = 0 (out is zero)
    epilogue();
    __syncthreads();

    for (int t = 1; t < NSTEPS - 1; ++t) {
#pragma unroll
        for (int p = 0; p < 4; ++p) { accr[p] *= 0.85f; acci[p] *= 0.85f; }
        if (mg == 3) {
            accr[4] *= 0.85f; acci[4] *= 0.85f;
            accr[5] *= 0.85f; acci[5] *= 0.85f;
        }
        if (t < INJ_ST) inj_add();

        // t=1: out(0) rows >=49 exactly zero (injection only) -> kt 0,1 only.
        const int ktEnd = (t == 1) ? 2 : 5;
        // kch 18,19 remap to chunk 17 (zeros both sides). unroll(1): R15.
#pragma unroll 1
        for (int kt = 0; kt < ktEnd; ++kt) {
            const int kch = kt * 4 + quad;
            const int rk  = (kch > 17) ? 17 : kch;
            const int ab  = (rk * MT + rb + ln15) * 8;
            bf16x8 ar0 = *(const bf16x8*)(CrL + ab);
            bf16x8 ar1 = *(const bf16x8*)(CrL + ab + 128);
            bf16x8 ai0 = *(const bf16x8*)(CiL + ab);
            bf16x8 ai1 = *(const bf16x8*)(CiL + ab + 128);
            bf16x8 ar2, ai2;
            if (mg == 3) {
                ar2 = *(const bf16x8*)(CrL + ab + 256);
                ai2 = *(const bf16x8*)(CiL + ab + 256);
            }
#pragma unroll
            for (int pn = 0; pn < 2; ++pn) {
                const int boff = (rk * 128 + (2 * ng + pn) * 16 + ln15) * 8;
                bf16x8 br = *(const bf16x8*)(OBr + boff);
                bf16x8 bi = *(const bf16x8*)(OBi + boff);
                bf16x8 bn = bneg(bi);
                CPAIR(ar0, ai0, br, bi, bn, pn)
                CPAIR(ar1, ai1, br, bi, bn, 2 + pn)
                if (mg == 3) { CPAIR(ar2, ai2, br, bi, bn, 4 + pn) }
            }
        }
        __syncthreads();   // all reads of OB done
        epilogue();
        __syncthreads();   // OB ready
    }

    // ---- t = 9: only rows 121..130 (tiles 7,8 = mg3 p2..5) feed energy.
    if (mg == 3) {
#pragma unroll
        for (int p = 2; p < 6; ++p) { accr[p] *= 0.85f; acci[p] *= 0.85f; }
#pragma unroll 1
        for (int kt = 0; kt < 5; ++kt) {
            const int kch = kt * 4 + quad;
            const int rk  = (kch > 17) ? 17 : kch;
            const int ab  = (rk * MT + 96 + ln15) * 8;     // rb = 96
            bf16x8 ar1 = *(const bf16x8*)(CrL + ab + 128); // tile 7
            bf16x8 ar2 = *(const bf16x8*)(CrL + ab + 256); // tile 8
            bf16x8 ai1 = *(const bf16x8*)(CiL + ab + 128);
            bf16x8 ai2 = *(const bf16x8*)(CiL + ab + 256);
#pragma unroll
            for (int pn = 0; pn < 2; ++pn) {
                const int boff = (rk * 128 + (2 * ng + pn) * 16 + ln15) * 8;
                bf16x8 br = *(const bf16x8*)(OBr + boff);
                bf16x8 bi = *(const bf16x8*)(OBi + boff);
                bf16x8 bn = bneg(bi);
                CPAIR(ar1, ai1, br, bi, bn, 2 + pn)
                CPAIR(ar2, ai2, br, bi, bn, 4 + pn)
            }
        }
    }
    __syncthreads();       // all CrL A-reads done before scrE (alias) writes

    if (mg == 3) {
        // energy rows: fp32 |out|^2 -> scrE (aliases CrL chunks 0..2)
#pragma unroll
        for (int p = 2; p < 6; ++p) {
            const int j0 = (p < 4) ? (112 + quad * 4) : (128 + quad * 4);
            const int n  = (2 * ng + (p & 1)) * 16 + ln15;
#pragma unroll
            for (int r = 0; r < 4; ++r) {
                int j = j0 + r;
                if (j >= 121 && j <= 130) {
                    float ar = accr[p][r], ai = acci[p][r];
                    float mag2 = fmaf(ar, ar, fmaf(ai, ai, 1.6e-7f));
                    float rsq  = __builtin_amdgcn_rsqf(mag2);
                    float e    = __builtin_amdgcn_exp2f(gsp2[j] * (mag2 * rsq));
                    float u    = __builtin_amdgcn_rcpf(1.0f + e);
                    float th   = fmaf(-2.0f, e * u, 1.0f);
                    float scv  = th * rsq;
                    float orv = ar * scv, oiv = ai * scv;
                    scrE[(j - 121) * 128 + n] = orv * orv + oiv * oiv;
                }
            }
        }
    }
    __syncthreads();       // scrE complete

    // ---- energy: scrE[10][128] holds exact fp32 |out|^2 ----
    if (tid < 10) {
        float ssum = 0.f;
        for (int cc = 0; cc < 128; ++cc) ssum += scrE[tid * 128 + cc];
        atomicAdd(energy + b * 10 + tid, ssum);
    }
}

__global__ void k_readout(const float* __restrict__ ws,
                          const float* __restrict__ W,
                          const float* __restrict__ bias,
                          float* __restrict__ out) {
    int i = blockIdx.x * 256 + threadIdx.x;
    if (i < 1280) {
        int b = i / 10, o = i % 10;
        float s = bias[o];
#pragma unroll
        for (int f = 0; f < 10; ++f) {
            float feat = log1pf(ws[WS_ENERGY + b * 10 + f] + 1e-8f);
            s = fmaf(feat, W[o * 10 + f], s);
        }
        out[i] = s;
    }
}

extern "C" void kernel_launch(void* const* d_in, const int* in_sizes, int n_in,
                              void* d_out, int out_size, void* d_ws, size_t ws_size,
                              hipStream_t stream) {
    const float* images = (const float*)d_in[0];
    const float* conn_r = (const float*)d_in[1];
    const float* conn_i = (const float*)d_in[2];
    const float* phase  = (const float*)d_in[3];
    const float* gain   = (const float*)d_in[4];
    const float* W      = (const float*)d_in[5];
    const float* bias   = (const float*)d_in[6];
    float* ws  = (float*)d_ws;
    float* out = (float*)d_out;

    hipLaunchKernelGGL(k_init, dim3(6), dim3(256), 0, stream, ws);
    hipLaunchKernelGGL(k_max, dim3(98), dim3(256), 0, stream, images, ws, 128 * 28 * 28);
    hipLaunchKernelGGL(k_prep, dim3(484), dim3(256), 0, stream,
                       images, conn_r, conn_i, phase, gain, ws);
    hipLaunchKernelGGL(k_main, dim3(1024), dim3(1024), 0, stream, ws, ws + WS_ENERGY);
    hipLaunchKernelGGL(k_readout, dim3(5), dim3(256), 0, stream, ws, W, bias, out);
}

// Round 4
// 278.401 us; speedup vs baseline: 1.7824x; 1.0221x over previous
//
#include <hip/hip_runtime.h>
#include <cmath>

// PhaseAwareClassifier on MI355X — R21: launch fusion + g2 hoist + setprio.
// R20 post-mortem: 16 waves works clean (VGPR 64, no scratch) but only -4%:
// step is a barrier-synced critical path, no pipe saturated (MFMA pipe ~42%
// of step, VALU ~16%, LDS ~50%; VALUBusy 63% = MFMA+VALU). Aux launches cost
// ~47 us of 284. R21 (GEMM schedule untouched):
//  1) k_init -> hipMemsetAsync (5.4 KB); k_max+k_prep fused (one dispatch).
//  2) inj array eliminated: k_main reads img directly, applies sc=1.02/mx
//     itself. px*sc rounds identically to the old stored value -> bit-exact.
//  3) g2 gain quads hoisted to registers before the t-loop (per-thread
//     constant; removes 4-6 global loads + vmcnt drain per step per wave).
//  4) s_setprio(1) around each kt MFMA burst (T5: mg3 1.5x heavier ->
//     role diversity between barriers).
// Bit-exact vs R20: same MFMA chain order, same epilogue float sequence.
// Discipline: unroll(1) kt loop (R15), constant acc indices (rule #20),
// __launch_bounds__(1024) only (R19/R20 lesson). LDS 156,672 B.

#define NSTEPS  10
#define INJ_ST  4
#define MT      144          // padded M (9 tiles of 16)

typedef __bf16 bf16x8 __attribute__((ext_vector_type(8)));
typedef __bf16 bf16x4 __attribute__((ext_vector_type(4)));
typedef short  short8 __attribute__((ext_vector_type(8)));
typedef float  f32x4  __attribute__((ext_vector_type(4)));

// workspace layout (float offsets)
#define WS_MAX    0          // 1      enc_max (uint-ordered float)
#define WS_ENERGY 64         // 1280   energy[b][10]
#define WS_GSP    2048       // 144    g2q[j] = -0.5*log2(e)*softplus(gain)
#define WS_CONN   4096       // 2 bf16 mats [20][144][8] chunked: Cr, Ci

// fused prep: blocks 0..97 = image absmax; blocks 98.. = conn + gsp tables
__global__ void k_pre(const float* __restrict__ img,
                      const float* __restrict__ cr, const float* __restrict__ ci,
                      const float* __restrict__ phase, const float* __restrict__ gain,
                      float* ws) {
    if (blockIdx.x < 98) {
        __shared__ float sm[256];
        float v = 0.f;
        for (int i = blockIdx.x * 256 + threadIdx.x; i < 128 * 28 * 28; i += 98 * 256)
            v = fmaxf(v, fabsf(img[i]));
        sm[threadIdx.x] = v;
        __syncthreads();
        for (int s = 128; s > 0; s >>= 1) {
            if (threadIdx.x < s) sm[threadIdx.x] = fmaxf(sm[threadIdx.x], sm[threadIdx.x + s]);
            __syncthreads();
        }
        if (threadIdx.x == 0)
            atomicMax((unsigned int*)(ws + WS_MAX), __float_as_uint(sm[0]));
        return;
    }
    int i = (blockIdx.x - 98) * 256 + threadIdx.x;
    __bf16* Cb = (__bf16*)(ws + WS_CONN);
    const int NCE = MT * 160;              // 23040 (m,k) pairs
    if (i < NCE) {
        int m = i / 160, k = i % 160;
        float vr = 0.f, vi = 0.f;
        if (m < 131 && k < 131) {
            float a = cr[k * 131 + m], b = ci[k * 131 + m];
            float ph = phase[m];
            float cp = cosf(ph), sp = sinf(ph);
            vr = a * cp - b * sp;
            vi = a * sp + b * cp;
        }
        int ca = ((k >> 3) * MT + m) * 8 + (k & 7);    // chunked addr
        Cb[ca]       = (__bf16)vr;
        Cb[NCE + ca] = (__bf16)vi;
    } else if (i < NCE + MT) {
        int j = i - NCE;
        float g = 0.f;
        if (j < 131) {
            float x = gain[j];
            g = (x > 20.f) ? x : log1pf(expf(x));  // softplus
        }
        ws[WS_GSP + j] = g * -0.72134754543f;       // -2*log2(e)*g / 4
    }
}

static __device__ __forceinline__ f32x4 MF(bf16x8 a, bf16x8 b, f32x4 c) {
    return __builtin_amdgcn_mfma_f32_16x16x32_bf16(a, b, c, 0, 0, 0);
}
static __device__ __forceinline__ bf16x8 bneg(bf16x8 a) {
    short8 t = __builtin_bit_cast(short8, a) ^ (short8)(short)0x8000;
    return __builtin_bit_cast(bf16x8, t);
}

// one complex 16x16 tile accumulation; order identical to R17..R20.
#define CPAIR(AR, AI, BR, BI, BNI, P)                                  \
    accr[P] = MF(AR, BR,  accr[P]);                                    \
    accr[P] = MF(AI, BNI, accr[P]);                                    \
    acci[P] = MF(AR, BI,  acci[P]);                                    \
    acci[P] = MF(AI, BR,  acci[P]);

__global__ __launch_bounds__(1024)
void k_main(const float* __restrict__ img, const float* __restrict__ ws,
            float* __restrict__ energy) {
    __shared__ __bf16 OB[2][18 * 128 * 8];         // 73,728 B: Or, Oi (18 ch)
    __shared__ __bf16 CrL[18 * MT * 8];            // 41,472 B: Cr (18 ch)
    __shared__ __bf16 CiL[18 * MT * 8];            // 41,472 B: Ci (18 ch)
    // total 156,672 B -> 1 block/CU, 16 waves = 4/SIMD.
    const int tid  = threadIdx.x;
    const int lane = tid & 63;
    const int ln15 = lane & 15;
    const int quad = lane >> 4;
    const int wv   = __builtin_amdgcn_readfirstlane(tid >> 6);  // 0..15
    const int mg   = wv >> 2;                       // 0..3
    const int ng   = wv & 3;                        // N-tiles 2ng, 2ng+1
    const int rb   = 32 * mg;                       // M-row base (mg3: 3 tiles)
    const int b    = blockIdx.x >> 3;               // 8 blocks per image

    const float* __restrict__ gsp2 = ws + WS_GSP;

    __bf16* __restrict__ OBr = &OB[0][0];
    __bf16* __restrict__ OBi = &OB[1][0];
    float* scrE = (float*)CrL;                      // alias: end only (t=9)

    // injection scaling (identical rounding to old k_prep: px*sc then *wls)
    const float mx = ws[WS_MAX];
    const float sc = (mx > 1e-8f) ? (1.02f / mx) : 1.02f;   // 0.85*4*0.3
    const int   imgb = b * 784 + (ln15 >> 2) * 28 + (ln15 & 3);

    // per-position encoding weight (pn = 0,1)
    float wls[2];
#pragma unroll
    for (int q = 0; q < 2; ++q) {
        int l = ((blockIdx.x & 7) * 8 + 2 * ng + q) & 63;
        wls[q] = 1.0f - fabsf((float)l - 32.0f) * (1.0f / 64.0f);
    }

    // hoisted gain quads (per-thread constant across all steps)
    f32x4 g2h[6];
#pragma unroll
    for (int p = 0; p < 6; ++p) {
        const int j0 = (p < 4) ? (rb + (p >> 1) * 16 + quad * 4) : (128 + quad * 4);
        g2h[p] = *(const f32x4*)(gsp2 + j0);
    }

    // stage Cr, Ci (chunks 0..17) -> LDS. No OB zero-init: t=0 epilogue
    // writes every OB cell (rows 0..143 across mg, all 128 cols).
    {
        const int4* srcR = (const int4*)(ws + WS_CONN);
        const int4* srcI = (const int4*)(ws + WS_CONN + (MT * 160 / 2)); // +20ch
        int4* dstR = (int4*)CrL;
        int4* dstI = (int4*)CiL;
        for (int i = tid; i < 2592; i += 1024) { dstR[i] = srcR[i]; dstI[i] = srcI[i]; }
    }

    f32x4 accr[6], acci[6];                         // p = mt*2 + pn, mt 0..2
#pragma unroll
    for (int p = 0; p < 6; ++p) { accr[p] = (f32x4)0.f; acci[p] = (f32x4)0.f; }

    // injection: rows j<49 live in mg0 (rows 0..31) and mg1 (rows 32..48).
    // Direct img gather: px*sc rounds identically to the old stored inj.
    auto inj_add = [&]() {
        if (mg <= 1) {
#pragma unroll
            for (int p = 0; p < 4; ++p) {
                const int j0 = rb + (p >> 1) * 16 + quad * 4;
#pragma unroll
                for (int r = 0; r < 4; ++r) {
                    int j = j0 + r;
                    if (j < 49) {
                        int pi = j / 7, pj = j % 7;
                        float px = img[imgb + pi * 112 + pj * 4];
                        float t  = px * sc;
                        accr[p][r] += t * wls[p & 1];
                    }
                }
            }
        }
    };

    // epilogue: out = a * tanh(g*|f|)/|f| with 0.25 folded into g2q.
    auto epi_one = [&](int p, int j0) {
        const int n = (2 * ng + (p & 1)) * 16 + ln15;
        bf16x4 pr, pi;
#pragma unroll
        for (int r = 0; r < 4; ++r) {
            float ar = accr[p][r], ai = acci[p][r];
            float mag2 = fmaf(ar, ar, fmaf(ai, ai, 1.6e-7f));
            float rsq  = __builtin_amdgcn_rsqf(mag2);
            float e    = __builtin_amdgcn_exp2f(g2h[p][r] * (mag2 * rsq));
            float u    = __builtin_amdgcn_rcpf(1.0f + e);
            float th   = fmaf(-2.0f, e * u, 1.0f);
            float scv  = th * rsq;
            pr[r] = (__bf16)(ar * scv); pi[r] = (__bf16)(ai * scv);
        }
        const int off = ((j0 >> 3) * 128 + n) * 8 + (j0 & 7);
        *(bf16x4*)(OBr + off) = pr;
        *(bf16x4*)(OBi + off) = pi;
    };
    auto epilogue = [&]() {
#pragma unroll
        for (int p = 0; p < 4; ++p) epi_one(p, rb + (p >> 1) * 16 + quad * 4);
        if (mg == 3) {
#pragma unroll
            for (int p = 4; p < 6; ++p) epi_one(p, 128 + quad * 4);
        }
    };

    __syncthreads();                                // CrL/CiL staged

    inj_add();                                      // t = 0 (out is zero)
    epilogue();
    __syncthreads();

    for (int t = 1; t < NSTEPS - 1; ++t) {
#pragma unroll
        for (int p = 0; p < 4; ++p) { accr[p] *= 0.85f; acci[p] *= 0.85f; }
        if (mg == 3) {
            accr[4] *= 0.85f; acci[4] *= 0.85f;
            accr[5] *= 0.85f; acci[5] *= 0.85f;
        }
        if (t < INJ_ST) inj_add();

        // t=1: out(0) rows >=49 exactly zero (injection only) -> kt 0,1 only.
        const int ktEnd = (t == 1) ? 2 : 5;
        // kch 18,19 remap to chunk 17 (zeros both sides). unroll(1): R15.
#pragma unroll 1
        for (int kt = 0; kt < ktEnd; ++kt) {
            const int kch = kt * 4 + quad;
            const int rk  = (kch > 17) ? 17 : kch;
            const int ab  = (rk * MT + rb + ln15) * 8;
            bf16x8 ar0 = *(const bf16x8*)(CrL + ab);
            bf16x8 ar1 = *(const bf16x8*)(CrL + ab + 128);
            bf16x8 ai0 = *(const bf16x8*)(CiL + ab);
            bf16x8 ai1 = *(const bf16x8*)(CiL + ab + 128);
            bf16x8 ar2, ai2;
            if (mg == 3) {
                ar2 = *(const bf16x8*)(CrL + ab + 256);
                ai2 = *(const bf16x8*)(CiL + ab + 256);
            }
            __builtin_amdgcn_s_setprio(1);
#pragma unroll
            for (int pn = 0; pn < 2; ++pn) {
                const int boff = (rk * 128 + (2 * ng + pn) * 16 + ln15) * 8;
                bf16x8 br = *(const bf16x8*)(OBr + boff);
                bf16x8 bi = *(const bf16x8*)(OBi + boff);
                bf16x8 bn = bneg(bi);
                CPAIR(ar0, ai0, br, bi, bn, pn)
                CPAIR(ar1, ai1, br, bi, bn, 2 + pn)
                if (mg == 3) { CPAIR(ar2, ai2, br, bi, bn, 4 + pn) }
            }
            __builtin_amdgcn_s_setprio(0);
        }
        __syncthreads();   // all reads of OB done
        epilogue();
        __syncthreads();   // OB ready
    }

    // ---- t = 9: only rows 121..130 (tiles 7,8 = mg3 p2..5) feed energy.
    if (mg == 3) {
#pragma unroll
        for (int p = 2; p < 6; ++p) { accr[p] *= 0.85f; acci[p] *= 0.85f; }
#pragma unroll 1
        for (int kt = 0; kt < 5; ++kt) {
            const int kch = kt * 4 + quad;
            const int rk  = (kch > 17) ? 17 : kch;
            const int ab  = (rk * MT + 96 + ln15) * 8;     // rb = 96
            bf16x8 ar1 = *(const bf16x8*)(CrL + ab + 128); // tile 7
            bf16x8 ar2 = *(const bf16x8*)(CrL + ab + 256); // tile 8
            bf16x8 ai1 = *(const bf16x8*)(CiL + ab + 128);
            bf16x8 ai2 = *(const bf16x8*)(CiL + ab + 256);
            __builtin_amdgcn_s_setprio(1);
#pragma unroll
            for (int pn = 0; pn < 2; ++pn) {
                const int boff = (rk * 128 + (2 * ng + pn) * 16 + ln15) * 8;
                bf16x8 br = *(const bf16x8*)(OBr + boff);
                bf16x8 bi = *(const bf16x8*)(OBi + boff);
                bf16x8 bn = bneg(bi);
                CPAIR(ar1, ai1, br, bi, bn, 2 + pn)
                CPAIR(ar2, ai2, br, bi, bn, 4 + pn)
            }
            __builtin_amdgcn_s_setprio(0);
        }
    }
    __syncthreads();       // all CrL A-reads done before scrE (alias) writes

    if (mg == 3) {
        // energy rows: fp32 |out|^2 -> scrE (aliases CrL chunks 0..2)
#pragma unroll
        for (int p = 2; p < 6; ++p) {
            const int j0 = (p < 4) ? (112 + quad * 4) : (128 + quad * 4);
            const int n  = (2 * ng + (p & 1)) * 16 + ln15;
#pragma unroll
            for (int r = 0; r < 4; ++r) {
                int j = j0 + r;
                if (j >= 121 && j <= 130) {
                    float ar = accr[p][r], ai = acci[p][r];
                    float mag2 = fmaf(ar, ar, fmaf(ai, ai, 1.6e-7f));
                    float rsq  = __builtin_amdgcn_rsqf(mag2);
                    float e    = __builtin_amdgcn_exp2f(g2h[p][r] * (mag2 * rsq));
                    float u    = __builtin_amdgcn_rcpf(1.0f + e);
                    float th   = fmaf(-2.0f, e * u, 1.0f);
                    float scv  = th * rsq;
                    float orv = ar * scv, oiv = ai * scv;
                    scrE[(j - 121) * 128 + n] = orv * orv + oiv * oiv;
                }
            }
        }
    }
    __syncthreads();       // scrE complete

    // ---- energy: scrE[10][128] holds exact fp32 |out|^2 ----
    if (tid < 10) {
        float ssum = 0.f;
        for (int cc = 0; cc < 128; ++cc) ssum += scrE[tid * 128 + cc];
        atomicAdd(energy + b * 10 + tid, ssum);
    }
}

__global__ void k_readout(const float* __restrict__ ws,
                          const float* __restrict__ W,
                          const float* __restrict__ bias,
                          float* __restrict__ out) {
    int i = blockIdx.x * 256 + threadIdx.x;
    if (i < 1280) {
        int b = i / 10, o = i % 10;
        float s = bias[o];
#pragma unroll
        for (int f = 0; f < 10; ++f) {
            float feat = log1pf(ws[WS_ENERGY + b * 10 + f] + 1e-8f);
            s = fmaf(feat, W[o * 10 + f], s);
        }
        out[i] = s;
    }
}

extern "C" void kernel_launch(void* const* d_in, const int* in_sizes, int n_in,
                              void* d_out, int out_size, void* d_ws, size_t ws_size,
                              hipStream_t stream) {
    const float* images = (const float*)d_in[0];
    const float* conn_r = (const float*)d_in[1];
    const float* conn_i = (const float*)d_in[2];
    const float* phase  = (const float*)d_in[3];
    const float* gain   = (const float*)d_in[4];
    const float* W      = (const float*)d_in[5];
    const float* bias   = (const float*)d_in[6];
    float* ws  = (float*)d_ws;
    float* out = (float*)d_out;

    // zero WS_MAX + energy (floats 0..1343) — stream-ordered, capture-safe
    hipMemsetAsync(ws, 0, (WS_ENERGY + 1280) * sizeof(float), stream);
    hipLaunchKernelGGL(k_pre, dim3(189), dim3(256), 0, stream,
                       images, conn_r, conn_i, phase, gain, ws);
    hipLaunchKernelGGL(k_main, dim3(1024), dim3(1024), 0, stream,
                       images, ws, ws + WS_ENERGY);
    hipLaunchKernelGGL(k_readout, dim3(5), dim3(256), 0, stream, ws, W, bias, out);
}